// Round 6
// baseline (224.290 us; speedup 1.0000x reference)
//
#include <hip/hip_runtime.h>
#include <hip/hip_bf16.h>

#define NN 4096      // n_nodes
#define FIN 1433     // in features
#define NH 8         // heads
#define DH 8         // per-head dim
#define HD 64        // NH*DH
#define KP 1472      // K padded to 23*64
#define NCH 23       // K chunks of 64
#define LOG2E 1.44269504f

typedef unsigned int u32;
typedef unsigned long long u64;
typedef float v2f __attribute__((ext_vector_type(2)));
typedef float v4f __attribute__((ext_vector_type(4)));
typedef short bf16x4 __attribute__((ext_vector_type(4)));
typedef short bf16x8 __attribute__((ext_vector_type(8)));

static __device__ __forceinline__ short f2bf(float f) {
    union { __hip_bfloat16 h; short s; } u; u.h = __float2bfloat16(f); return u.s;
}
__device__ __forceinline__ float lo_bf(u32 u) {
    union { u32 u; float f; } v; v.u = u << 16; return v.f;
}
__device__ __forceinline__ float hi_bf(u32 u) {
    union { u32 u; float f; } v; v.u = u & 0xffff0000u; return v.f;
}

// ---------------- kernel 0: Wt[n][k] = bf16(W[k][n]), k zero-padded to 1472 --
__global__ __launch_bounds__(256) void k_wprep(const float* __restrict__ W,
                                               short* __restrict__ Wt) {
    __shared__ float Ts[64][65];
    const int c = blockIdx.x;
    const int u = threadIdx.x;
    const int n4 = (u & 15) * 4;
    const int kr = u >> 4;
#pragma unroll
    for (int q = 0; q < 4; ++q) {
        const int kl = kr + q * 16;
        const int kg = c * 64 + kl;
        v4f v = {0.f, 0.f, 0.f, 0.f};
        if (kg < FIN) v = *(const v4f*)&W[(size_t)kg * HD + n4];
        *(v4f*)&Ts[kl][n4] = v;
    }
    __syncthreads();
    const int n = u >> 2;
    const int koff = (u & 3) * 16;
    __align__(16) short tmp[16];
#pragma unroll
    for (int r = 0; r < 16; ++r) tmp[r] = f2bf(Ts[koff + r][n]);
    *(uint4*)&Wt[(size_t)n * KP + c * 64 + koff]     = *(uint4*)&tmp[0];
    *(uint4*)&Wt[(size_t)n * KP + c * 64 + koff + 8] = *(uint4*)&tmp[8];
}

// ---------------- kernel 1: g = vert @ W via bf16 MFMA, + sl/sr epilogue -----
__global__ __launch_bounds__(256) void k_gemm(
    const float* __restrict__ vert, const short* __restrict__ Wt,
    const float* __restrict__ al, const float* __restrict__ ar,
    short* __restrict__ gbf, float* __restrict__ sl, float* __restrict__ sr)
{
    __shared__ short As[2][16][72];
    __shared__ short Bs[2][64][72];

    const int t  = threadIdx.x;
    const int i0 = blockIdx.x * 16;
    const int am = t >> 4, ak = (t & 15) * 4;
    const int bn = t >> 2, bk = (t & 3) * 16;
    const int lane = t & 63, wv = t >> 6;
    const int ml = lane & 15, quad = lane >> 4;
    const int n0 = wv * 16;

    v4f pa; uint4 pb0, pb1;
    pa  = *(const v4f*)&vert[(size_t)(i0 + am) * FIN + ak];
    pb0 = *(const uint4*)&Wt[(size_t)bn * KP + bk];
    pb1 = *(const uint4*)&Wt[(size_t)bn * KP + bk + 8];
    {
        bf16x4 s = {f2bf(pa.x), f2bf(pa.y), f2bf(pa.z), f2bf(pa.w)};
        *(bf16x4*)&As[0][am][ak] = s;
        *(uint4*)&Bs[0][bn][bk]     = pb0;
        *(uint4*)&Bs[0][bn][bk + 8] = pb1;
    }
    __syncthreads();

    v4f acc = {0.f, 0.f, 0.f, 0.f};
    for (int c = 0; c < NCH; ++c) {
        const int cb = c & 1, nb = cb ^ 1;
        const bool pf = (c + 1) < NCH;
        if (pf) {
            const int k0 = (c + 1) * 64 + ak;
            if (k0 + 3 < FIN) {
                pa = *(const v4f*)&vert[(size_t)(i0 + am) * FIN + k0];
            } else {
#pragma unroll
                for (int e = 0; e < 4; ++e)
                    pa[e] = (k0 + e < FIN) ? vert[(size_t)(i0 + am) * FIN + k0 + e] : 0.f;
            }
            pb0 = *(const uint4*)&Wt[(size_t)bn * KP + (c + 1) * 64 + bk];
            pb1 = *(const uint4*)&Wt[(size_t)bn * KP + (c + 1) * 64 + bk + 8];
        }
        {
            const bf16x8 a0 = *(const bf16x8*)&As[cb][ml][quad * 8];
            const bf16x8 b0 = *(const bf16x8*)&Bs[cb][n0 + ml][quad * 8];
            acc = __builtin_amdgcn_mfma_f32_16x16x32_bf16(a0, b0, acc, 0, 0, 0);
            const bf16x8 a1 = *(const bf16x8*)&As[cb][ml][quad * 8 + 32];
            const bf16x8 b1 = *(const bf16x8*)&Bs[cb][n0 + ml][quad * 8 + 32];
            acc = __builtin_amdgcn_mfma_f32_16x16x32_bf16(a1, b1, acc, 0, 0, 0);
        }
        if (pf) {
            bf16x4 s = {f2bf(pa.x), f2bf(pa.y), f2bf(pa.z), f2bf(pa.w)};
            *(bf16x4*)&As[nb][am][ak] = s;
            *(uint4*)&Bs[nb][bn][bk]     = pb0;
            *(uint4*)&Bs[nb][bn][bk + 8] = pb1;
        }
        __syncthreads();
    }

    // C/D layout (16x16x32): n = lane&15, m = quad*4 + reg
    const int n = n0 + ml;
#pragma unroll
    for (int r = 0; r < 4; ++r)
        gbf[(size_t)(i0 + quad * 4 + r) * HD + n] = f2bf(acc[r]);

    const float aln = al[n], arn = ar[n];
    float vl[4], vr[4];
#pragma unroll
    for (int r = 0; r < 4; ++r) { vl[r] = acc[r] * aln; vr[r] = acc[r] * arn; }
#pragma unroll
    for (int off = 1; off < 8; off <<= 1) {
#pragma unroll
        for (int r = 0; r < 4; ++r) {
            vl[r] += __shfl_xor(vl[r], off, 64);
            vr[r] += __shfl_xor(vr[r], off, 64);
        }
    }
    if ((lane & 7) == 0) {
        const int h = n >> 3;
#pragma unroll
        for (int r = 0; r < 4; ++r) {   // pre-scaled by log2(e): attn uses exp2
            sl[(i0 + quad * 4 + r) * NH + h] = vl[r] * LOG2E;
            sr[(i0 + quad * 4 + r) * NH + h] = vr[r] * LOG2E;
        }
    }
}

// ---------------- kernel 2: masked softmax attention + aggregate + ELU -------
// 512 blocks x 256 thr. Thread = (slice s in [0,32), head h), owns ALL 8 i-rows
// of the block -> each 16B bf16 G-read serves 8 visits. Mask as column-bytes.
__global__ __launch_bounds__(256) void k_attn(
    const int* __restrict__ edge, const short* __restrict__ gbf,
    const float* __restrict__ sl, const float* __restrict__ sr,
    float* __restrict__ out)
{
    __shared__ __align__(16) short gsb[2][64][64];   // bf16 G chunk, 16 KB
    __shared__ float srch[2][NH][66];                // sr transposed, bank-padded
    __shared__ unsigned char mb[2][64];              // per-column mask bytes

    const int t  = threadIdx.x;
    const int i0 = blockIdx.x * 8;
    const int h  = t & 7;
    const int s  = t >> 3;             // slice 0..31 -> j in {2s, 2s+1}

    float sli[8];
#pragma unroll
    for (int i = 0; i < 8; ++i) sli[i] = sl[(i0 + i) * NH + h];   // log2e-scaled

    // staging roles
    const int jr = t >> 3;             // G rows jr, jr+32
    const int go = (t & 7) * 8;        // 8 bf16 (16B) within row

    uint4 pg0, pg1; float ps0, ps1; int pe[8];
    {   // chunk 0 loads
        pg0 = *(const uint4*)&gbf[(size_t)jr * HD + go];
        pg1 = *(const uint4*)&gbf[(size_t)(jr + 32) * HD + go];
        ps0 = sr[t]; ps1 = sr[t + 256];
        if (t < 64) {
#pragma unroll
            for (int i = 0; i < 8; ++i) pe[i] = edge[(size_t)(i0 + i) * NN + t];
        }
    }
    *(uint4*)&gsb[0][jr][go]      = pg0;
    *(uint4*)&gsb[0][jr + 32][go] = pg1;
    srch[0][t & 7][t >> 3] = ps0;
    srch[0][(t + 256) & 7][(t + 256) >> 3] = ps1;
    if (t < 64) {
        u32 m = 0;
#pragma unroll
        for (int i = 0; i < 8; ++i) m |= (pe[i] != 0) ? (1u << i) : 0u;
        mb[0][t] = (unsigned char)m;
    }
    __syncthreads();

    v2f acc[8][4];
#pragma unroll
    for (int i = 0; i < 8; ++i)
#pragma unroll
        for (int k = 0; k < 4; ++k) acc[i][k] = (v2f){0.f, 0.f};
    float la[8] = {0,0,0,0,0,0,0,0};

    for (int c = 0; c < NN / 64; ++c) {
        const int cb = c & 1, nb = cb ^ 1;
        const bool pf = (c + 1) < NN / 64;
        if (pf) {
            const int j0 = (c + 1) * 64;
            pg0 = *(const uint4*)&gbf[(size_t)(j0 + jr) * HD + go];
            pg1 = *(const uint4*)&gbf[(size_t)(j0 + jr + 32) * HD + go];
            ps0 = sr[j0 * NH + t]; ps1 = sr[j0 * NH + t + 256];
            if (t < 64) {
#pragma unroll
                for (int i = 0; i < 8; ++i) pe[i] = edge[(size_t)(i0 + i) * NN + j0 + t];
            }
        }
        // ---- compute on buffer cb ----
        const float2 sv = *(const float2*)&srch[cb][h][2 * s];
        const u32 mm = *(const unsigned short*)&mb[cb][2 * s];
#pragma unroll
        for (int jj = 0; jj < 2; ++jj) {
            const int j = 2 * s + jj;
            const uint4 gv = *(const uint4*)&gsb[cb][j][h * 8];
            const float g0 = lo_bf(gv.x), g1 = hi_bf(gv.x);
            const float g2 = lo_bf(gv.y), g3 = hi_bf(gv.y);
            const float g4 = lo_bf(gv.z), g5 = hi_bf(gv.z);
            const float g6 = lo_bf(gv.w), g7 = hi_bf(gv.w);
            const float srv = jj ? sv.y : sv.x;
            const u32 mbyte = (mm >> (8 * jj)) & 0xffu;
#pragma unroll
            for (int i = 0; i < 8; ++i) {
                float e = sli[i] + srv;
                e = fmaxf(e, 0.2f * e);                  // leaky (log2-domain)
                e = ((mbyte >> i) & 1u) ? e : -1e9f;     // mask -> exp2 = 0
                const float w = exp2f(e);
                la[i] += w;
                const v2f w2 = {w, w};
                acc[i][0] += w2 * (v2f){g0, g1};
                acc[i][1] += w2 * (v2f){g2, g3};
                acc[i][2] += w2 * (v2f){g4, g5};
                acc[i][3] += w2 * (v2f){g6, g7};
            }
        }
        if (pf) {
            *(uint4*)&gsb[nb][jr][go]      = pg0;
            *(uint4*)&gsb[nb][jr + 32][go] = pg1;
            srch[nb][t & 7][t >> 3] = ps0;
            srch[nb][(t + 256) & 7][(t + 256) >> 3] = ps1;
            if (t < 64) {
                u32 m = 0;
#pragma unroll
                for (int i = 0; i < 8; ++i) m |= (pe[i] != 0) ? (1u << i) : 0u;
                mb[nb][t] = (unsigned char)m;
            }
        }
        __syncthreads();
    }

    // butterfly over lane bits 3..5 (slice-within-wave); every lane ends with
    // the wave-total for its head h.
#pragma unroll
    for (int off = 8; off < 64; off <<= 1) {
#pragma unroll
        for (int i = 0; i < 8; ++i) {
            la[i] += __shfl_xor(la[i], off, 64);
#pragma unroll
            for (int k = 0; k < 4; ++k) {
                acc[i][k].x += __shfl_xor(acc[i][k].x, off, 64);
                acc[i][k].y += __shfl_xor(acc[i][k].y, off, 64);
            }
        }
    }

    float* red = (float*)&gsb[0][0][0];   // 4 waves x 8 h x 72 f32 = 9.2 KB
    if ((t & 63) < 8) {
        float* r = red + ((t >> 6) * 8 + h) * 72;
#pragma unroll
        for (int i = 0; i < 8; ++i) {
#pragma unroll
            for (int k = 0; k < 4; ++k) *(float2*)&r[i * 8 + 2 * k] = (float2){acc[i][k].x, acc[i][k].y};
            r[64 + i] = la[i];
        }
    }
    __syncthreads();

#pragma unroll
    for (int o = t; o < 512; o += 256) {
        const int i = o >> 6, hd = o & 63;
        const int hh = hd >> 3, dd = hd & 7;
        float num = 0.f, den = 0.f;
#pragma unroll
        for (int w = 0; w < 4; ++w) {
            num += red[(w * 8 + hh) * 72 + i * 8 + dd];
            den += red[(w * 8 + hh) * 72 + 64 + i];
        }
        float x = num / den;
        x = (x > 0.f) ? x : (__expf(x) - 1.f);   // ELU
        out[(size_t)(i0 + i) * HD + hd] = x;
    }
}

extern "C" void kernel_launch(void* const* d_in, const int* in_sizes, int n_in,
                              void* d_out, int out_size, void* d_ws, size_t ws_size,
                              hipStream_t stream) {
    const float* vert = (const float*)d_in[0];
    const int*   edge = (const int*)d_in[1];
    const float* W    = (const float*)d_in[2];
    const float* al   = (const float*)d_in[3];
    const float* ar   = (const float*)d_in[4];
    float* out = (float*)d_out;

    char* ws = (char*)d_ws;
    short* gbf = (short*)ws;                                  // 512 KB bf16 g
    float* sl  = (float*)(ws + 512 * 1024);                   // 128 KB
    float* sr  = (float*)(ws + 512 * 1024 + 128 * 1024);      // 128 KB
    short* Wt  = (short*)(ws + 768 * 1024);                   // 184 KB

    hipLaunchKernelGGL(k_wprep, dim3(NCH), dim3(256), 0, stream, W, Wt);
    hipLaunchKernelGGL(k_gemm, dim3(NN / 16), dim3(256), 0, stream,
                       vert, Wt, al, ar, gbf, sl, sr);
    hipLaunchKernelGGL(k_attn, dim3(NN / 8), dim3(256), 0, stream,
                       edge, gbf, sl, sr, out);
}

// Round 7
// 215.848 us; speedup vs baseline: 1.0391x; 1.0391x over previous
//
#include <hip/hip_runtime.h>
#include <hip/hip_bf16.h>

#define NN 4096      // n_nodes
#define FIN 1433     // in features
#define NH 8         // heads
#define DH 8         // per-head dim
#define HD 64        // NH*DH
#define KP 1472      // K padded to 46*32
#define LOG2E 1.44269504f

typedef unsigned int u32;
typedef unsigned long long u64;
typedef float v2f __attribute__((ext_vector_type(2)));
typedef float v4f __attribute__((ext_vector_type(4)));
typedef short bf16x4 __attribute__((ext_vector_type(4)));
typedef short bf16x8 __attribute__((ext_vector_type(8)));

static __device__ __forceinline__ short f2bf(float f) {
    union { __hip_bfloat16 h; short s; } u; u.h = __float2bfloat16(f); return u.s;
}
__device__ __forceinline__ float lo_bf(u32 u) {
    union { u32 u; float f; } v; v.u = u << 16; return v.f;
}
__device__ __forceinline__ float hi_bf(u32 u) {
    union { u32 u; float f; } v; v.u = u & 0xffff0000u; return v.f;
}

// ---------------- kernel 0: Wt[n][k] = bf16(W[k][n]), k zero-padded to 1472 --
__global__ __launch_bounds__(256) void k_wprep(const float* __restrict__ W,
                                               short* __restrict__ Wt) {
    __shared__ float Ts[64][65];
    const int c = blockIdx.x;
    const int u = threadIdx.x;
    const int n4 = (u & 15) * 4;
    const int kr = u >> 4;
#pragma unroll
    for (int q = 0; q < 4; ++q) {
        const int kl = kr + q * 16;
        const int kg = c * 64 + kl;
        v4f v = {0.f, 0.f, 0.f, 0.f};
        if (kg < FIN) v = *(const v4f*)&W[(size_t)kg * HD + n4];
        *(v4f*)&Ts[kl][n4] = v;
    }
    __syncthreads();
    const int n = u >> 2;
    const int koff = (u & 3) * 16;
    __align__(16) short tmp[16];
#pragma unroll
    for (int r = 0; r < 16; ++r) tmp[r] = f2bf(Ts[koff + r][n]);
    *(uint4*)&Wt[(size_t)n * KP + c * 64 + koff]     = *(uint4*)&tmp[0];
    *(uint4*)&Wt[(size_t)n * KP + c * 64 + koff + 8] = *(uint4*)&tmp[8];
}

// ---------------- kernel 1: g = vert @ W via MFMA, barrier-free K-split ------
// 256 blocks x 4 waves. Wave w owns k-chunks c ≡ w (mod 4), 32 k each, no LDS
// in the K-loop; one LDS combine + epilogue at the end.
__global__ __launch_bounds__(256, 4) void k_gemm(
    const float* __restrict__ vert, const short* __restrict__ Wt,
    const float* __restrict__ al, const float* __restrict__ ar,
    short* __restrict__ gbf, float* __restrict__ sl, float* __restrict__ sr)
{
    __shared__ float cacc[4][16][64];   // 16 KB

    const int t = threadIdx.x, lane = t & 63, w = t >> 6;
    const int ml = lane & 15, q = lane >> 4;
    const int i0 = blockIdx.x * 16;
    const float* vrow = vert + (size_t)(i0 + ml) * FIN;

    v4f acc[4];
#pragma unroll
    for (int g = 0; g < 4; ++g) acc[g] = (v4f){0.f, 0.f, 0.f, 0.f};

    for (int c = w; c < 45; c += 4) {
        const int k0 = c * 32 + q * 8;
        v4f a0, a1;
        if (k0 + 7 < FIN) {
            a0 = *(const v4f*)&vrow[k0];
            a1 = *(const v4f*)&vrow[k0 + 4];
        } else {
            float tmp[8];
#pragma unroll
            for (int e = 0; e < 8; ++e)
                tmp[e] = (k0 + e < FIN) ? vrow[k0 + e] : 0.f;
            a0 = (v4f){tmp[0], tmp[1], tmp[2], tmp[3]};
            a1 = (v4f){tmp[4], tmp[5], tmp[6], tmp[7]};
        }
        const bf16x8 af = {f2bf(a0.x), f2bf(a0.y), f2bf(a0.z), f2bf(a0.w),
                           f2bf(a1.x), f2bf(a1.y), f2bf(a1.z), f2bf(a1.w)};
#pragma unroll
        for (int g = 0; g < 4; ++g) {
            const bf16x8 bf = *(const bf16x8*)&Wt[(size_t)(g * 16 + ml) * KP + k0];
            acc[g] = __builtin_amdgcn_mfma_f32_16x16x32_bf16(af, bf, acc[g], 0, 0, 0);
        }
    }

    // C/D layout: n = lane&15, m = quad*4 + r. Dump partials, combine.
#pragma unroll
    for (int g = 0; g < 4; ++g)
#pragma unroll
        for (int r = 0; r < 4; ++r)
            cacc[w][q * 4 + r][g * 16 + ml] = acc[g][r];
    __syncthreads();

    const int m = t >> 4, n4 = (t & 15) * 4;
    v4f s = (v4f){0.f, 0.f, 0.f, 0.f};
#pragma unroll
    for (int ww = 0; ww < 4; ++ww) s += *(const v4f*)&cacc[ww][m][n4];

    const bf16x4 gs4 = {f2bf(s.x), f2bf(s.y), f2bf(s.z), f2bf(s.w)};
    *(bf16x4*)&gbf[(size_t)(i0 + m) * HD + n4] = gs4;

    float pl = s.x * al[n4] + s.y * al[n4 + 1] + s.z * al[n4 + 2] + s.w * al[n4 + 3];
    float pr = s.x * ar[n4] + s.y * ar[n4 + 1] + s.z * ar[n4 + 2] + s.w * ar[n4 + 3];
    pl += __shfl_xor(pl, 1, 64);
    pr += __shfl_xor(pr, 1, 64);
    if ((t & 1) == 0) {
        const int h = (t & 15) >> 1;
        sl[(i0 + m) * NH + h] = pl * LOG2E;   // pre-scale: attn uses exp2
        sr[(i0 + m) * NH + h] = pr * LOG2E;
    }
}

// ---------------- kernel 2: masked softmax attention + aggregate + ELU -------
// 1024 blocks (i-tile 4) x 256 thr, 4 blocks/CU. Thread = (slice s, head h),
// owns the 4 i-rows; acc = 32 VGPRs (no spill under launch_bounds(256,4)).
__global__ __launch_bounds__(256, 4) void k_attn(
    const int* __restrict__ edge, const short* __restrict__ gbf,
    const float* __restrict__ sl, const float* __restrict__ sr,
    float* __restrict__ out)
{
    __shared__ __align__(16) short gsb[2][64][64];   // 16 KB (buf0 reused as red)
    __shared__ float srs[2][64][8];                  // 4 KB
    __shared__ unsigned char mb[2][64];              // mask: 4 i-bits per column

    const int t  = threadIdx.x;
    const int i0 = blockIdx.x * 4;
    const int h  = t & 7;
    const int s  = t >> 3;             // 0..31: j in {2s, 2s+1}
    const int wv = t >> 6;

    float sli[4];
#pragma unroll
    for (int i = 0; i < 4; ++i) sli[i] = sl[(i0 + i) * NH + h];   // log2e-scaled

    const int r0 = t >> 3;             // G staging rows r0, r0+32
    const int gg = (t & 7) * 8;

    uint4 pg0, pg1; float pv0, pv1; int pe0 = 0, pe1 = 0, pe2 = 0, pe3 = 0;
    {   // chunk 0
        pg0 = *(const uint4*)&gbf[(size_t)r0 * HD + gg];
        pg1 = *(const uint4*)&gbf[(size_t)(r0 + 32) * HD + gg];
        pv0 = sr[t]; pv1 = sr[t + 256];
        if (t < 64) {
            pe0 = edge[(size_t)(i0 + 0) * NN + t];
            pe1 = edge[(size_t)(i0 + 1) * NN + t];
            pe2 = edge[(size_t)(i0 + 2) * NN + t];
            pe3 = edge[(size_t)(i0 + 3) * NN + t];
        }
    }
    *(uint4*)&gsb[0][r0][gg]      = pg0;
    *(uint4*)&gsb[0][r0 + 32][gg] = pg1;
    srs[0][t >> 3][t & 7] = pv0;
    srs[0][(t >> 3) + 32][t & 7] = pv1;
    if (t < 64) {
        u32 m = (pe0 != 0 ? 1u : 0u) | (pe1 != 0 ? 2u : 0u) |
                (pe2 != 0 ? 4u : 0u) | (pe3 != 0 ? 8u : 0u);
        mb[0][t] = (unsigned char)m;
    }
    __syncthreads();

    v2f acc[4][4];
#pragma unroll
    for (int i = 0; i < 4; ++i)
#pragma unroll
        for (int k = 0; k < 4; ++k) acc[i][k] = (v2f){0.f, 0.f};
    float la[4] = {0.f, 0.f, 0.f, 0.f};

    for (int c = 0; c < NN / 64; ++c) {
        const int cb = c & 1, nb = cb ^ 1;
        const bool pf = (c + 1) < NN / 64;
        if (pf) {
            const int j0 = (c + 1) * 64;
            pg0 = *(const uint4*)&gbf[(size_t)(j0 + r0) * HD + gg];
            pg1 = *(const uint4*)&gbf[(size_t)(j0 + r0 + 32) * HD + gg];
            pv0 = sr[(size_t)j0 * NH + t];
            pv1 = sr[(size_t)j0 * NH + t + 256];
            if (t < 64) {
                pe0 = edge[(size_t)(i0 + 0) * NN + j0 + t];
                pe1 = edge[(size_t)(i0 + 1) * NN + j0 + t];
                pe2 = edge[(size_t)(i0 + 2) * NN + j0 + t];
                pe3 = edge[(size_t)(i0 + 3) * NN + j0 + t];
            }
        }
        const u32 mm = *(const unsigned short*)&mb[cb][2 * s];
#pragma unroll
        for (int jj = 0; jj < 2; ++jj) {
            const int j = 2 * s + jj;
            const uint4 gv = *(const uint4*)&gsb[cb][j][h * 8];
            const float g0 = lo_bf(gv.x), g1 = hi_bf(gv.x);
            const float g2 = lo_bf(gv.y), g3 = hi_bf(gv.y);
            const float g4 = lo_bf(gv.z), g5 = hi_bf(gv.z);
            const float g6 = lo_bf(gv.w), g7 = hi_bf(gv.w);
            const float srv = srs[cb][j][h];
            const u32 mk = mm >> (8 * jj);
#pragma unroll
            for (int i = 0; i < 4; ++i) {
                float e = sli[i] + srv;
                e = fmaxf(e, 0.2f * e);                  // leaky (log2 domain)
                e = ((mk >> i) & 1u) ? e : -1e9f;        // mask -> exp2 = 0
                const float wgt = exp2f(e);
                la[i] += wgt;
                const v2f w2 = {wgt, wgt};
                acc[i][0] += w2 * (v2f){g0, g1};
                acc[i][1] += w2 * (v2f){g2, g3};
                acc[i][2] += w2 * (v2f){g4, g5};
                acc[i][3] += w2 * (v2f){g6, g7};
            }
        }
        if (pf) {
            *(uint4*)&gsb[nb][r0][gg]      = pg0;
            *(uint4*)&gsb[nb][r0 + 32][gg] = pg1;
            srs[nb][t >> 3][t & 7] = pv0;
            srs[nb][(t >> 3) + 32][t & 7] = pv1;
            if (t < 64) {
                u32 m = (pe0 != 0 ? 1u : 0u) | (pe1 != 0 ? 2u : 0u) |
                        (pe2 != 0 ? 4u : 0u) | (pe3 != 0 ? 8u : 0u);
                mb[nb][t] = (unsigned char)m;
            }
        }
        __syncthreads();
    }

    // butterfly over lane bits 3..5 (slice-within-wave)
#pragma unroll
    for (int off = 8; off < 64; off <<= 1) {
#pragma unroll
        for (int i = 0; i < 4; ++i) {
            la[i] += __shfl_xor(la[i], off, 64);
#pragma unroll
            for (int k = 0; k < 4; ++k) {
                acc[i][k].x += __shfl_xor(acc[i][k].x, off, 64);
                acc[i][k].y += __shfl_xor(acc[i][k].y, off, 64);
            }
        }
    }

    float* red = (float*)&gsb[0][0][0];   // 4 waves x 8 h x 36 f32 = 4.6 KB
    if (((t >> 3) & 7) == 0) {            // one lane per (wave, h)
        float* rp = red + (wv * 8 + h) * 36;
#pragma unroll
        for (int i = 0; i < 4; ++i) {
#pragma unroll
            for (int k = 0; k < 4; ++k) {
                rp[i * 8 + 2 * k]     = acc[i][k].x;
                rp[i * 8 + 2 * k + 1] = acc[i][k].y;
            }
            rp[32 + i] = la[i];
        }
    }
    __syncthreads();

    {   // 256 outputs: i = t>>6, (h,d) = t&63
        const int i = t >> 6, hd = t & 63, hh = hd >> 3, dd = hd & 7;
        float num = 0.f, den = 0.f;
#pragma unroll
        for (int ww = 0; ww < 4; ++ww) {
            num += red[(ww * 8 + hh) * 36 + i * 8 + dd];
            den += red[(ww * 8 + hh) * 36 + 32 + i];
        }
        float x = num / den;
        x = (x > 0.f) ? x : (__expf(x) - 1.f);   // ELU
        out[(size_t)(i0 + i) * HD + hd] = x;
    }
}

extern "C" void kernel_launch(void* const* d_in, const int* in_sizes, int n_in,
                              void* d_out, int out_size, void* d_ws, size_t ws_size,
                              hipStream_t stream) {
    const float* vert = (const float*)d_in[0];
    const int*   edge = (const int*)d_in[1];
    const float* W    = (const float*)d_in[2];
    const float* al   = (const float*)d_in[3];
    const float* ar   = (const float*)d_in[4];
    float* out = (float*)d_out;

    char* ws = (char*)d_ws;
    short* gbf = (short*)ws;                                  // 512 KB bf16 g
    float* sl  = (float*)(ws + 512 * 1024);                   // 128 KB
    float* sr  = (float*)(ws + 512 * 1024 + 128 * 1024);      // 128 KB
    short* Wt  = (short*)(ws + 768 * 1024);                   // 184 KB

    hipLaunchKernelGGL(k_wprep, dim3(23), dim3(256), 0, stream, W, Wt);
    hipLaunchKernelGGL(k_gemm, dim3(NN / 16), dim3(256), 0, stream,
                       vert, Wt, al, ar, gbf, sl, sr);
    hipLaunchKernelGGL(k_attn, dim3(NN / 4), dim3(256), 0, stream,
                       edge, gbf, sl, sr, out);
}

// Round 8
// 195.123 us; speedup vs baseline: 1.1495x; 1.1062x over previous
//
#include <hip/hip_runtime.h>
#include <hip/hip_bf16.h>

#define NN 4096      // n_nodes
#define FIN 1433     // in features
#define NH 8         // heads
#define DH 8         // per-head dim
#define HD 64        // NH*DH
#define KP 1472      // K padded to 46*32
#define LOG2E 1.44269504f

typedef unsigned int u32;
typedef unsigned long long u64;
typedef float v4f __attribute__((ext_vector_type(4)));
typedef short bf16x4 __attribute__((ext_vector_type(4)));
typedef short bf16x8 __attribute__((ext_vector_type(8)));

static __device__ __forceinline__ short f2bf(float f) {
    union { __hip_bfloat16 h; short s; } u; u.h = __float2bfloat16(f); return u.s;
}

// ---------------- kernel 0: Wt[n][k] = bf16(W[k][n]), k zero-padded to 1472 --
__global__ __launch_bounds__(256) void k_wprep(const float* __restrict__ W,
                                               short* __restrict__ Wt) {
    __shared__ float Ts[64][65];
    const int c = blockIdx.x;
    const int u = threadIdx.x;
    const int n4 = (u & 15) * 4;
    const int kr = u >> 4;
#pragma unroll
    for (int q = 0; q < 4; ++q) {
        const int kl = kr + q * 16;
        const int kg = c * 64 + kl;
        v4f v = {0.f, 0.f, 0.f, 0.f};
        if (kg < FIN) v = *(const v4f*)&W[(size_t)kg * HD + n4];
        *(v4f*)&Ts[kl][n4] = v;
    }
    __syncthreads();
    const int n = u >> 2;
    const int koff = (u & 3) * 16;
    __align__(16) short tmp[16];
#pragma unroll
    for (int r = 0; r < 16; ++r) tmp[r] = f2bf(Ts[koff + r][n]);
    *(uint4*)&Wt[(size_t)n * KP + c * 64 + koff]     = *(uint4*)&tmp[0];
    *(uint4*)&Wt[(size_t)n * KP + c * 64 + koff + 8] = *(uint4*)&tmp[8];
}

// ---------------- kernel 1: g = vert @ W via MFMA, barrier-free K-split ------
// Epilogue writes g TRANSPOSED: gT[hd][node] bf16, plus log2e-scaled sl/sr.
__global__ __launch_bounds__(256, 4) void k_gemm(
    const float* __restrict__ vert, const short* __restrict__ Wt,
    const float* __restrict__ al, const float* __restrict__ ar,
    short* __restrict__ gT, float* __restrict__ sl, float* __restrict__ sr)
{
    __shared__ float cacc[4][16][64];   // 16 KB

    const int t = threadIdx.x, lane = t & 63, w = t >> 6;
    const int ml = lane & 15, q = lane >> 4;
    const int i0 = blockIdx.x * 16;
    const float* vrow = vert + (size_t)(i0 + ml) * FIN;

    v4f acc[4];
#pragma unroll
    for (int g = 0; g < 4; ++g) acc[g] = (v4f){0.f, 0.f, 0.f, 0.f};

    for (int c = w; c < 45; c += 4) {
        const int k0 = c * 32 + q * 8;
        v4f a0, a1;
        if (k0 + 7 < FIN) {
            a0 = *(const v4f*)&vrow[k0];
            a1 = *(const v4f*)&vrow[k0 + 4];
        } else {
            float tmp[8];
#pragma unroll
            for (int e = 0; e < 8; ++e)
                tmp[e] = (k0 + e < FIN) ? vrow[k0 + e] : 0.f;
            a0 = (v4f){tmp[0], tmp[1], tmp[2], tmp[3]};
            a1 = (v4f){tmp[4], tmp[5], tmp[6], tmp[7]};
        }
        const bf16x8 af = {f2bf(a0.x), f2bf(a0.y), f2bf(a0.z), f2bf(a0.w),
                           f2bf(a1.x), f2bf(a1.y), f2bf(a1.z), f2bf(a1.w)};
#pragma unroll
        for (int g = 0; g < 4; ++g) {
            const bf16x8 bf = *(const bf16x8*)&Wt[(size_t)(g * 16 + ml) * KP + k0];
            acc[g] = __builtin_amdgcn_mfma_f32_16x16x32_bf16(af, bf, acc[g], 0, 0, 0);
        }
    }

#pragma unroll
    for (int g = 0; g < 4; ++g)
#pragma unroll
        for (int r = 0; r < 4; ++r)
            cacc[w][q * 4 + r][g * 16 + ml] = acc[g][r];
    __syncthreads();

    const int m = t >> 4, n4 = (t & 15) * 4;
    v4f s = (v4f){0.f, 0.f, 0.f, 0.f};
#pragma unroll
    for (int ww = 0; ww < 4; ++ww) s += *(const v4f*)&cacc[ww][m][n4];

#pragma unroll
    for (int e = 0; e < 4; ++e)        // transposed store: gT[hd][node]
        gT[(size_t)(n4 + e) * NN + i0 + m] = f2bf(s[e]);

    float pl = s.x * al[n4] + s.y * al[n4 + 1] + s.z * al[n4 + 2] + s.w * al[n4 + 3];
    float pr = s.x * ar[n4] + s.y * ar[n4 + 1] + s.z * ar[n4 + 2] + s.w * ar[n4 + 3];
    pl += __shfl_xor(pl, 1, 64);
    pr += __shfl_xor(pr, 1, 64);
    if ((t & 1) == 0) {
        const int h = (t & 15) >> 1;
        sl[(i0 + m) * NH + h] = pl * LOG2E;   // pre-scale: attn uses exp2
        sr[(i0 + m) * NH + h] = pr * LOG2E;
    }
}

// ---------------- kernel 2: MFMA flash-attention ----------------------------
// grid (256, 2): blockIdx.x = 16-row i-tile, blockIdx.y = h-group (4 heads).
// Wave w owns head h = hg*4+w for ALL 4096 j. Per 32-j chunk: build P in
// MFMA A-frag layout in registers (exp2 of masked leaky), B = staged G^T rows
// for this head + a ones-row in column 8 -> same MFMA yields numerators AND
// the softmax denominator. acc = 4 VGPRs; no cross-wave reduction.
__global__ __launch_bounds__(256) void k_attn(
    const int* __restrict__ edge, const short* __restrict__ gT,
    const float* __restrict__ sl, const float* __restrict__ sr,
    float* __restrict__ out)
{
    __shared__ __align__(16) short Gt[2][33][40];   // rows 0..31 g-dims, 32=ones
    __shared__ __align__(16) float srs[2][4][36];   // [h-local][j]
    __shared__ u32 mrow[2][16];                     // adjacency bits per i-row

    const int t = threadIdx.x;
    const int lane = t & 63, w = t >> 6;
    const int ml = lane & 15, quad = lane >> 4;
    const int i0 = blockIdx.x * 16;
    const int hg = blockIdx.y;
    const int h  = hg * 4 + w;

    const float sli = sl[(i0 + ml) * NH + h];   // log2e-scaled

    // staging roles
    const int grow = t >> 2;            // t<128: Gt row 0..31
    const int gseg = (t & 3) * 8;
    const int srj = t >> 2, srh = t & 3;
    const int mr = w * 4 + (lane >> 5); // ballot rows mr, mr+2
    const int mj = lane & 31;

    if (t < 32) { Gt[0][32][t] = 0x3f80; Gt[1][32][t] = 0x3f80; }  // ones rows

    uint4 pgv; float psr; int pe0, pe1;
    if (t < 128) {
        pgv = *(const uint4*)&gT[(size_t)(hg * 32 + grow) * NN + gseg];
        psr = sr[(size_t)srj * NH + hg * 4 + srh];
    }
    pe0 = edge[(size_t)(i0 + mr) * NN + mj];
    pe1 = edge[(size_t)(i0 + mr + 2) * NN + mj];

    if (t < 128) {
        *(uint4*)&Gt[0][grow][gseg] = pgv;
        srs[0][srh][srj] = psr;
    }
    {
        u64 b0 = __ballot(pe0 != 0), b1 = __ballot(pe1 != 0);
        if (lane == 0)  { mrow[0][w * 4]     = (u32)b0;         mrow[0][w * 4 + 2] = (u32)b1; }
        if (lane == 32) { mrow[0][w * 4 + 1] = (u32)(b0 >> 32); mrow[0][w * 4 + 3] = (u32)(b1 >> 32); }
    }
    __syncthreads();

    v4f acc = {0.f, 0.f, 0.f, 0.f};

    for (int c = 0; c < NN / 32; ++c) {
        const int cb = c & 1, nb = cb ^ 1;
        const bool pf = (c + 1) < NN / 32;
        if (pf) {
            const int j0 = (c + 1) * 32;
            if (t < 128) {
                pgv = *(const uint4*)&gT[(size_t)(hg * 32 + grow) * NN + j0 + gseg];
                psr = sr[(size_t)(j0 + srj) * NH + hg * 4 + srh];
            }
            pe0 = edge[(size_t)(i0 + mr) * NN + j0 + mj];
            pe1 = edge[(size_t)(i0 + mr + 2) * NN + j0 + mj];
        }
        // ---- compute on buffer cb ----
        const v4f s0 = *(const v4f*)&srs[cb][w][quad * 8];
        const v4f s1 = *(const v4f*)&srs[cb][w][quad * 8 + 4];
        const u32 mw = mrow[cb][ml] >> (quad * 8);
        const int brow = (ml < 8) ? (w * 8 + ml) : 32;
        const bf16x8 bfrag = *(const bf16x8*)&Gt[cb][brow][quad * 8];

        float e[8] = {sli + s0.x, sli + s0.y, sli + s0.z, sli + s0.w,
                      sli + s1.x, sli + s1.y, sli + s1.z, sli + s1.w};
        short pw[8];
#pragma unroll
        for (int jj = 0; jj < 8; ++jj) {
            float x = fmaxf(e[jj], 0.2f * e[jj]);      // leaky (log2 domain)
            x = ((mw >> jj) & 1u) ? x : -1e9f;         // mask -> exp2 = 0
            pw[jj] = f2bf(exp2f(x));
        }
        const bf16x8 afrag = {pw[0], pw[1], pw[2], pw[3], pw[4], pw[5], pw[6], pw[7]};
        acc = __builtin_amdgcn_mfma_f32_16x16x32_bf16(afrag, bfrag, acc, 0, 0, 0);

        if (pf) {
            if (t < 128) {
                *(uint4*)&Gt[nb][grow][gseg] = pgv;
                srs[nb][srh][srj] = psr;
            }
            u64 b0 = __ballot(pe0 != 0), b1 = __ballot(pe1 != 0);
            if (lane == 0)  { mrow[nb][w * 4]     = (u32)b0;         mrow[nb][w * 4 + 2] = (u32)b1; }
            if (lane == 32) { mrow[nb][w * 4 + 1] = (u32)(b0 >> 32); mrow[nb][w * 4 + 3] = (u32)(b1 >> 32); }
        }
        __syncthreads();
    }

    // C layout: col n = ml, row m = quad*4 + r. Col 8 = denominator.
#pragma unroll
    for (int r = 0; r < 4; ++r) {
        const float den = __shfl(acc[r], quad * 16 + 8, 64);
        if (ml < 8) {
            float x = acc[r] / den;
            x = (x > 0.f) ? x : (__expf(x) - 1.f);     // ELU
            out[(size_t)(i0 + quad * 4 + r) * HD + h * 8 + ml] = x;
        }
    }
}

extern "C" void kernel_launch(void* const* d_in, const int* in_sizes, int n_in,
                              void* d_out, int out_size, void* d_ws, size_t ws_size,
                              hipStream_t stream) {
    const float* vert = (const float*)d_in[0];
    const int*   edge = (const int*)d_in[1];
    const float* W    = (const float*)d_in[2];
    const float* al   = (const float*)d_in[3];
    const float* ar   = (const float*)d_in[4];
    float* out = (float*)d_out;

    char* ws = (char*)d_ws;
    short* gT = (short*)ws;                                   // 512 KB bf16 g^T
    float* sl = (float*)(ws + 512 * 1024);                    // 128 KB
    float* sr = (float*)(ws + 512 * 1024 + 128 * 1024);       // 128 KB
    short* Wt = (short*)(ws + 768 * 1024);                    // 184 KB

    hipLaunchKernelGGL(k_wprep, dim3(23), dim3(256), 0, stream, W, Wt);
    hipLaunchKernelGGL(k_gemm, dim3(NN / 16), dim3(256), 0, stream,
                       vert, Wt, al, ar, gT, sl, sr);
    hipLaunchKernelGGL(k_attn, dim3(NN / 16, 2), dim3(256), 0, stream,
                       edge, gT, sl, sr, out);
}

// Round 9
// 172.545 us; speedup vs baseline: 1.2999x; 1.1309x over previous
//
#include <hip/hip_runtime.h>
#include <hip/hip_bf16.h>

#define NN 4096      // n_nodes
#define FIN 1433     // in features
#define NH 8         // heads
#define DH 8         // per-head dim
#define HD 64        // NH*DH
#define KP 1472      // K padded to 46*32
#define LOG2E 1.44269504f

typedef unsigned int u32;
typedef unsigned long long u64;
typedef float v4f __attribute__((ext_vector_type(4)));
typedef short bf16x4 __attribute__((ext_vector_type(4)));
typedef short bf16x8 __attribute__((ext_vector_type(8)));

static __device__ __forceinline__ short f2bf(float f) {
    union { __hip_bfloat16 h; short s; } u; u.h = __float2bfloat16(f); return u.s;
}

// ---------------- kernel 0: Wt[n][k] = bf16(W[k][n]), k zero-padded to 1472 --
__global__ __launch_bounds__(256) void k_wprep(const float* __restrict__ W,
                                               short* __restrict__ Wt) {
    __shared__ float Ts[64][65];
    const int c = blockIdx.x;
    const int u = threadIdx.x;
    const int n4 = (u & 15) * 4;
    const int kr = u >> 4;
#pragma unroll
    for (int q = 0; q < 4; ++q) {
        const int kl = kr + q * 16;
        const int kg = c * 64 + kl;
        v4f v = {0.f, 0.f, 0.f, 0.f};
        if (kg < FIN) v = *(const v4f*)&W[(size_t)kg * HD + n4];
        *(v4f*)&Ts[kl][n4] = v;
    }
    __syncthreads();
    const int n = u >> 2;
    const int koff = (u & 3) * 16;
    __align__(16) short tmp[16];
#pragma unroll
    for (int r = 0; r < 16; ++r) tmp[r] = f2bf(Ts[koff + r][n]);
    *(uint4*)&Wt[(size_t)n * KP + c * 64 + koff]     = *(uint4*)&tmp[0];
    *(uint4*)&Wt[(size_t)n * KP + c * 64 + koff + 8] = *(uint4*)&tmp[8];
}

// ---------------- kernel 1: g = vert @ W via MFMA, barrier-free K-split ------
// Epilogue: gT[hd][node] bf16, sl[node][h], srT[h][node] (both log2e-scaled).
__global__ __launch_bounds__(256, 4) void k_gemm(
    const float* __restrict__ vert, const short* __restrict__ Wt,
    const float* __restrict__ al, const float* __restrict__ ar,
    short* __restrict__ gT, float* __restrict__ sl, float* __restrict__ srT)
{
    __shared__ float cacc[4][16][64];   // 16 KB

    const int t = threadIdx.x, lane = t & 63, w = t >> 6;
    const int ml = lane & 15, q = lane >> 4;
    const int i0 = blockIdx.x * 16;
    const float* vrow = vert + (size_t)(i0 + ml) * FIN;

    v4f acc[4];
#pragma unroll
    for (int g = 0; g < 4; ++g) acc[g] = (v4f){0.f, 0.f, 0.f, 0.f};

    for (int c = w; c < 45; c += 4) {
        const int k0 = c * 32 + q * 8;
        v4f a0, a1;
        if (k0 + 7 < FIN) {
            a0 = *(const v4f*)&vrow[k0];
            a1 = *(const v4f*)&vrow[k0 + 4];
        } else {
            float tmp[8];
#pragma unroll
            for (int e = 0; e < 8; ++e)
                tmp[e] = (k0 + e < FIN) ? vrow[k0 + e] : 0.f;
            a0 = (v4f){tmp[0], tmp[1], tmp[2], tmp[3]};
            a1 = (v4f){tmp[4], tmp[5], tmp[6], tmp[7]};
        }
        const bf16x8 af = {f2bf(a0.x), f2bf(a0.y), f2bf(a0.z), f2bf(a0.w),
                           f2bf(a1.x), f2bf(a1.y), f2bf(a1.z), f2bf(a1.w)};
#pragma unroll
        for (int g = 0; g < 4; ++g) {
            const bf16x8 bf = *(const bf16x8*)&Wt[(size_t)(g * 16 + ml) * KP + k0];
            acc[g] = __builtin_amdgcn_mfma_f32_16x16x32_bf16(af, bf, acc[g], 0, 0, 0);
        }
    }

#pragma unroll
    for (int g = 0; g < 4; ++g)
#pragma unroll
        for (int r = 0; r < 4; ++r)
            cacc[w][q * 4 + r][g * 16 + ml] = acc[g][r];
    __syncthreads();

    const int m = t >> 4, n4 = (t & 15) * 4;
    v4f s = (v4f){0.f, 0.f, 0.f, 0.f};
#pragma unroll
    for (int ww = 0; ww < 4; ++ww) s += *(const v4f*)&cacc[ww][m][n4];

#pragma unroll
    for (int e = 0; e < 4; ++e)        // transposed store: gT[hd][node]
        gT[(size_t)(n4 + e) * NN + i0 + m] = f2bf(s[e]);

    float pl = s.x * al[n4] + s.y * al[n4 + 1] + s.z * al[n4 + 2] + s.w * al[n4 + 3];
    float pr = s.x * ar[n4] + s.y * ar[n4 + 1] + s.z * ar[n4 + 2] + s.w * ar[n4 + 3];
    pl += __shfl_xor(pl, 1, 64);
    pr += __shfl_xor(pr, 1, 64);
    if ((t & 1) == 0) {
        const int h = (t & 15) >> 1;
        sl[(i0 + m) * NH + h]  = pl * LOG2E;   // pre-scale: attn uses exp2
        srT[h * NN + i0 + m]   = pr * LOG2E;
    }
}

// ---------------- kernel 2: MFMA flash-attention, 128-j chunks, j-split ------
// grid (256, 2, 2): x = 16-row i-tile, y = h-group (4 heads), z = j-half.
// Wave w = head hg*4+w. Per 128-j chunk: 4 MFMAs; P built in A-frag layout via
// exp2(masked leaky); ones-row in B col 8 gives the denominator in the same
// MFMA. Partial num/den to workspace; k_comb finishes.
__global__ __launch_bounds__(256, 4) void k_attn(
    const int* __restrict__ edge, const short* __restrict__ gT,
    const float* __restrict__ sl, const float* __restrict__ srT,
    float* __restrict__ numw, float* __restrict__ denw)
{
    __shared__ __align__(16) short Gt[2][33][136];   // rows 0..31 dims, 32=ones
    __shared__ __align__(16) float srs[2][4][132];   // [h-local][j in chunk]
    __shared__ u32 mrow[2][16][5];                   // [i-row][j-word], padded

    const int t = threadIdx.x;
    const int lane = t & 63, w = t >> 6;
    const int ml = lane & 15, quad = lane >> 4;
    const int i0 = blockIdx.x * 16;
    const int hg = blockIdx.y;
    const int js = blockIdx.z;
    const int jbase = js * 2048;
    const int h  = hg * 4 + w;

    const float sli = sl[(i0 + ml) * NH + h];   // log2e-scaled

    // staging roles
    const int r2 = t >> 4, seg = (t & 15) * 8;     // Gt rows r2, r2+16
    const int shl = t >> 5 >= 4 ? 0 : t >> 5;      // srs head (t<128)
    const int sj4 = (t & 31) * 4;
    const int half = lane >> 5 ? 1 : 0;            // ballot halves (unused var)

    if (t < 16) {   // ones rows, both buffers
        const u32 ones2 = 0x3f803f80u;
        uint4 o4 = {ones2, ones2, ones2, ones2};
        *(uint4*)&Gt[0][32][t * 8] = o4;
        *(uint4*)&Gt[1][32][t * 8] = o4;
    }

    const short* gTh = gT + (hg * 32) * NN;
    const float* srh = srT + (hg * 4) * NN;

    uint4 pg0, pg1; v4f psr; int pe[8];
    {   // chunk 0 loads
        pg0 = *(const uint4*)&gTh[r2 * NN + jbase + seg];
        pg1 = *(const uint4*)&gTh[(r2 + 16) * NN + jbase + seg];
        if (t < 128) psr = *(const v4f*)&srh[shl * NN + jbase + sj4];
#pragma unroll
        for (int rr = 0; rr < 4; ++rr) {
            pe[rr * 2]     = edge[(i0 + w * 4 + rr) * NN + jbase + (lane & 63)];
            pe[rr * 2 + 1] = edge[(i0 + w * 4 + rr) * NN + jbase + 64 + (lane & 63)];
        }
    }
    *(uint4*)&Gt[0][r2][seg]      = pg0;
    *(uint4*)&Gt[0][r2 + 16][seg] = pg1;
    if (t < 128) *(v4f*)&srs[0][shl][sj4] = psr;
#pragma unroll
    for (int rr = 0; rr < 4; ++rr) {
        u64 b0 = __ballot(pe[rr * 2] != 0);
        u64 b1 = __ballot(pe[rr * 2 + 1] != 0);
        if (lane == 0)  { mrow[0][w * 4 + rr][0] = (u32)b0;         mrow[0][w * 4 + rr][2] = (u32)b1; }
        if (lane == 32) { mrow[0][w * 4 + rr][1] = (u32)(b0 >> 32); mrow[0][w * 4 + rr][3] = (u32)(b1 >> 32); }
    }
    __syncthreads();

    v4f acc = {0.f, 0.f, 0.f, 0.f};

    for (int c = 0; c < 16; ++c) {
        const int cb = c & 1, nb = cb ^ 1;
        const bool pf = (c + 1) < 16;
        if (pf) {
            const int j0 = jbase + (c + 1) * 128;
            pg0 = *(const uint4*)&gTh[r2 * NN + j0 + seg];
            pg1 = *(const uint4*)&gTh[(r2 + 16) * NN + j0 + seg];
            if (t < 128) psr = *(const v4f*)&srh[shl * NN + j0 + sj4];
#pragma unroll
            for (int rr = 0; rr < 4; ++rr) {
                pe[rr * 2]     = edge[(i0 + w * 4 + rr) * NN + j0 + (lane & 63)];
                pe[rr * 2 + 1] = edge[(i0 + w * 4 + rr) * NN + j0 + 64 + (lane & 63)];
            }
        }
        // ---- compute: 4 sub-chunks of 32 j ----
        const int brow = (ml < 8) ? (w * 8 + ml) : 32;
#pragma unroll
        for (int s = 0; s < 4; ++s) {
            const v4f s0 = *(const v4f*)&srs[cb][w][s * 32 + quad * 8];
            const v4f s1 = *(const v4f*)&srs[cb][w][s * 32 + quad * 8 + 4];
            const u32 mw = mrow[cb][ml][s] >> (quad * 8);
            const bf16x8 bfrag = *(const bf16x8*)&Gt[cb][brow][s * 32 + quad * 8];

            float e0 = sli + s0.x, e1 = sli + s0.y, e2 = sli + s0.z, e3 = sli + s0.w;
            float e4 = sli + s1.x, e5 = sli + s1.y, e6 = sli + s1.z, e7 = sli + s1.w;
            float p[8];
            p[0] = exp2f((mw & 1u)   ? fmaxf(e0, 0.2f * e0) : -1e9f);
            p[1] = exp2f((mw & 2u)   ? fmaxf(e1, 0.2f * e1) : -1e9f);
            p[2] = exp2f((mw & 4u)   ? fmaxf(e2, 0.2f * e2) : -1e9f);
            p[3] = exp2f((mw & 8u)   ? fmaxf(e3, 0.2f * e3) : -1e9f);
            p[4] = exp2f((mw & 16u)  ? fmaxf(e4, 0.2f * e4) : -1e9f);
            p[5] = exp2f((mw & 32u)  ? fmaxf(e5, 0.2f * e5) : -1e9f);
            p[6] = exp2f((mw & 64u)  ? fmaxf(e6, 0.2f * e6) : -1e9f);
            p[7] = exp2f((mw & 128u) ? fmaxf(e7, 0.2f * e7) : -1e9f);
            // truncating bf16 pack: one v_perm per pair
            u32 w01 = __builtin_amdgcn_perm(__float_as_uint(p[1]), __float_as_uint(p[0]), 0x07060302u);
            u32 w23 = __builtin_amdgcn_perm(__float_as_uint(p[3]), __float_as_uint(p[2]), 0x07060302u);
            u32 w45 = __builtin_amdgcn_perm(__float_as_uint(p[5]), __float_as_uint(p[4]), 0x07060302u);
            u32 w67 = __builtin_amdgcn_perm(__float_as_uint(p[7]), __float_as_uint(p[6]), 0x07060302u);
            uint4 au = {w01, w23, w45, w67};
            const bf16x8 afrag = *(const bf16x8*)&au;
            acc = __builtin_amdgcn_mfma_f32_16x16x32_bf16(afrag, bfrag, acc, 0, 0, 0);
        }
        if (pf) {
            *(uint4*)&Gt[nb][r2][seg]      = pg0;
            *(uint4*)&Gt[nb][r2 + 16][seg] = pg1;
            if (t < 128) *(v4f*)&srs[nb][shl][sj4] = psr;
#pragma unroll
            for (int rr = 0; rr < 4; ++rr) {
                u64 b0 = __ballot(pe[rr * 2] != 0);
                u64 b1 = __ballot(pe[rr * 2 + 1] != 0);
                if (lane == 0)  { mrow[nb][w * 4 + rr][0] = (u32)b0;         mrow[nb][w * 4 + rr][2] = (u32)b1; }
                if (lane == 32) { mrow[nb][w * 4 + rr][1] = (u32)(b0 >> 32); mrow[nb][w * 4 + rr][3] = (u32)(b1 >> 32); }
            }
        }
        __syncthreads();
    }

    // C layout: col = ml (0..7 dims, 8 = denominator), row = quad*4 + r
    float* nw = numw + (size_t)js * NN * HD;
    float* dw = denw + (size_t)js * NN * NH;
    const int iA = i0 + quad * 4;
#pragma unroll
    for (int r = 0; r < 4; ++r) {
        if (ml < 8)       nw[(iA + r) * HD + h * 8 + ml] = acc[r];
        else if (ml == 8) dw[(iA + r) * NH + h]          = acc[r];
    }
}

// ---------------- kernel 3: combine j-split partials, div, ELU ---------------
__global__ __launch_bounds__(256) void k_comb(
    const float* __restrict__ numw, const float* __restrict__ denw,
    float* __restrict__ out)
{
    const int gid = blockIdx.x * 256 + threadIdx.x;   // 0 .. NN*HD-1
    const int i = gid >> 6, h = (gid & 63) >> 3;
    const float num = numw[gid] + numw[NN * HD + gid];
    const float den = denw[i * NH + h] + denw[NN * NH + i * NH + h];
    float x = num / den;
    out[gid] = (x > 0.f) ? x : (__expf(x) - 1.f);     // ELU
}

extern "C" void kernel_launch(void* const* d_in, const int* in_sizes, int n_in,
                              void* d_out, int out_size, void* d_ws, size_t ws_size,
                              hipStream_t stream) {
    const float* vert = (const float*)d_in[0];
    const int*   edge = (const int*)d_in[1];
    const float* W    = (const float*)d_in[2];
    const float* al   = (const float*)d_in[3];
    const float* ar   = (const float*)d_in[4];
    float* out = (float*)d_out;

    char* ws = (char*)d_ws;
    short* gT   = (short*)ws;                                 // 512 KB
    float* sl   = (float*)(ws + 512 * 1024);                  // 128 KB
    float* srT  = (float*)(ws + 640 * 1024);                  // 128 KB
    short* Wt   = (short*)(ws + 768 * 1024);                  // 184 KB
    float* numw = (float*)(ws + 1024 * 1024);                 // 2 MB (2 splits)
    float* denw = (float*)(ws + 3 * 1024 * 1024);             // 256 KB

    hipLaunchKernelGGL(k_wprep, dim3(23), dim3(256), 0, stream, W, Wt);
    hipLaunchKernelGGL(k_gemm, dim3(NN / 16), dim3(256), 0, stream,
                       vert, Wt, al, ar, gT, sl, srT);
    hipLaunchKernelGGL(k_attn, dim3(NN / 16, 2, 2), dim3(256), 0, stream,
                       edge, gT, sl, srT, numw, denw);
    hipLaunchKernelGGL(k_comb, dim3(NN * HD / 256), dim3(256), 0, stream,
                       numw, denw, out);
}

// Round 10
// 150.078 us; speedup vs baseline: 1.4945x; 1.1497x over previous
//
#include <hip/hip_runtime.h>
#include <hip/hip_bf16.h>

#define NN 4096      // n_nodes
#define FIN 1433     // in features
#define NH 8         // heads
#define DH 8         // per-head dim
#define HD 64        // NH*DH
#define KP 1472      // K padded to 46*32
#define LOG2E 1.44269504f
#define NJS 4        // j-splits

typedef unsigned int u32;
typedef unsigned long long u64;
typedef float v4f __attribute__((ext_vector_type(4)));
typedef short bf16x4 __attribute__((ext_vector_type(4)));
typedef short bf16x8 __attribute__((ext_vector_type(8)));

static __device__ __forceinline__ short f2bf(float f) {
    union { __hip_bfloat16 h; short s; } u; u.h = __float2bfloat16(f); return u.s;
}

// ---------------- kernel 0: Wt[n][k] = bf16(W[k][n]), k zero-padded to 1472 --
__global__ __launch_bounds__(256) void k_wprep(const float* __restrict__ W,
                                               short* __restrict__ Wt) {
    __shared__ float Ts[64][65];
    const int c = blockIdx.x;
    const int u = threadIdx.x;
    const int n4 = (u & 15) * 4;
    const int kr = u >> 4;
#pragma unroll
    for (int q = 0; q < 4; ++q) {
        const int kl = kr + q * 16;
        const int kg = c * 64 + kl;
        v4f v = {0.f, 0.f, 0.f, 0.f};
        if (kg < FIN) v = *(const v4f*)&W[(size_t)kg * HD + n4];
        *(v4f*)&Ts[kl][n4] = v;
    }
    __syncthreads();
    const int n = u >> 2;
    const int koff = (u & 3) * 16;
    __align__(16) short tmp[16];
#pragma unroll
    for (int r = 0; r < 16; ++r) tmp[r] = f2bf(Ts[koff + r][n]);
    *(uint4*)&Wt[(size_t)n * KP + c * 64 + koff]     = *(uint4*)&tmp[0];
    *(uint4*)&Wt[(size_t)n * KP + c * 64 + koff + 8] = *(uint4*)&tmp[8];
}

// ---------------- kernel 1: g = vert @ W via MFMA, barrier-free K-split ------
// Epilogue: gT[hd][node] bf16; eAC[node][h] = {exp(sl), exp(0.2 sl)};
// eB[h][node] = exp(sr); eD[h][node] = exp(0.2 sr).
__global__ __launch_bounds__(256, 4) void k_gemm(
    const float* __restrict__ vert, const short* __restrict__ Wt,
    const float* __restrict__ al, const float* __restrict__ ar,
    short* __restrict__ gT, float2* __restrict__ eAC,
    float* __restrict__ eB, float* __restrict__ eD)
{
    __shared__ float cacc[4][16][64];   // 16 KB

    const int t = threadIdx.x, lane = t & 63, w = t >> 6;
    const int ml = lane & 15, q = lane >> 4;
    const int i0 = blockIdx.x * 16;
    const float* vrow = vert + (size_t)(i0 + ml) * FIN;

    v4f acc[4];
#pragma unroll
    for (int g = 0; g < 4; ++g) acc[g] = (v4f){0.f, 0.f, 0.f, 0.f};

    for (int c = w; c < 45; c += 4) {
        const int k0 = c * 32 + q * 8;
        v4f a0, a1;
        if (k0 + 7 < FIN) {
            a0 = *(const v4f*)&vrow[k0];
            a1 = *(const v4f*)&vrow[k0 + 4];
        } else {
            float tmp[8];
#pragma unroll
            for (int e = 0; e < 8; ++e)
                tmp[e] = (k0 + e < FIN) ? vrow[k0 + e] : 0.f;
            a0 = (v4f){tmp[0], tmp[1], tmp[2], tmp[3]};
            a1 = (v4f){tmp[4], tmp[5], tmp[6], tmp[7]};
        }
        const bf16x8 af = {f2bf(a0.x), f2bf(a0.y), f2bf(a0.z), f2bf(a0.w),
                           f2bf(a1.x), f2bf(a1.y), f2bf(a1.z), f2bf(a1.w)};
#pragma unroll
        for (int g = 0; g < 4; ++g) {
            const bf16x8 bf = *(const bf16x8*)&Wt[(size_t)(g * 16 + ml) * KP + k0];
            acc[g] = __builtin_amdgcn_mfma_f32_16x16x32_bf16(af, bf, acc[g], 0, 0, 0);
        }
    }

#pragma unroll
    for (int g = 0; g < 4; ++g)
#pragma unroll
        for (int r = 0; r < 4; ++r)
            cacc[w][q * 4 + r][g * 16 + ml] = acc[g][r];
    __syncthreads();

    const int m = t >> 4, n4 = (t & 15) * 4;
    v4f s = (v4f){0.f, 0.f, 0.f, 0.f};
#pragma unroll
    for (int ww = 0; ww < 4; ++ww) s += *(const v4f*)&cacc[ww][m][n4];

#pragma unroll
    for (int e = 0; e < 4; ++e)        // transposed store: gT[hd][node]
        gT[(size_t)(n4 + e) * NN + i0 + m] = f2bf(s[e]);

    float pl = s.x * al[n4] + s.y * al[n4 + 1] + s.z * al[n4 + 2] + s.w * al[n4 + 3];
    float pr = s.x * ar[n4] + s.y * ar[n4 + 1] + s.z * ar[n4 + 2] + s.w * ar[n4 + 3];
    pl += __shfl_xor(pl, 1, 64);
    pr += __shfl_xor(pr, 1, 64);
    if ((t & 1) == 0) {
        const int h = (t & 15) >> 1;
        const int node = i0 + m;
        eAC[node * NH + h] = make_float2(exp2f(pl * LOG2E), exp2f(0.2f * pl * LOG2E));
        eB[h * NN + node] = exp2f(pr * LOG2E);
        eD[h * NN + node] = exp2f(0.2f * pr * LOG2E);
    }
}

// ---------------- kernel 2: MFMA flash-attention, exp-free inner loop --------
// grid (256, 2, 4): x = 16-row i-tile, y = h-group (4 heads), z = j-quarter.
// P[i,j] = max(A_i*B_j, C_i*D_j) (== exp(leaky(sl+sr)), exact identity),
// masked -> 0. P packed (truncating) to bf16 in MFMA A-frag layout; B-frag =
// staged G^T rows + ones-row -> same MFMA yields numerators AND denominator.
__global__ __launch_bounds__(256, 4) void k_attn(
    const int* __restrict__ edge, const short* __restrict__ gT,
    const float2* __restrict__ eAC, const float* __restrict__ eB,
    const float* __restrict__ eD,
    float* __restrict__ numw, float* __restrict__ denw)
{
    __shared__ __align__(16) short Gt[2][33][136];   // rows 0..31 dims, 32=ones
    __shared__ __align__(16) float srB[2][4][132];   // [h-local][j in chunk]
    __shared__ __align__(16) float srD[2][4][132];
    __shared__ u32 mrow[2][16][5];                   // [i-row][j-word], padded

    const int t = threadIdx.x;
    const int lane = t & 63, w = t >> 6;
    const int ml = lane & 15, quad = lane >> 4;
    const int i0 = blockIdx.x * 16;
    const int hg = blockIdx.y;
    const int js = blockIdx.z;
    const int jbase = js * (NN / NJS);
    const int h  = hg * 4 + w;

    const float2 acv = eAC[(i0 + ml) * NH + h];
    const float Ai = acv.x, Ci = acv.y;

    // staging roles
    const int r2 = t >> 4, seg = (t & 15) * 8;     // Gt rows r2, r2+16
    const int shl = (t >> 5) & 3;                  // srB/srD head (t<128)
    const int sj4 = (t & 31) * 4;

    if (t < 16) {   // ones rows, both buffers
        const u32 ones2 = 0x3f803f80u;
        uint4 o4 = {ones2, ones2, ones2, ones2};
        *(uint4*)&Gt[0][32][t * 8] = o4;
        *(uint4*)&Gt[1][32][t * 8] = o4;
    }

    const short* gTh = gT + (hg * 32) * NN;
    const float* eBh = eB + (hg * 4) * NN;
    const float* eDh = eD + (hg * 4) * NN;

    uint4 pg0, pg1; v4f psb, psd; int pe[8];
    {   // chunk 0 loads
        pg0 = *(const uint4*)&gTh[r2 * NN + jbase + seg];
        pg1 = *(const uint4*)&gTh[(r2 + 16) * NN + jbase + seg];
        if (t < 128) {
            psb = *(const v4f*)&eBh[shl * NN + jbase + sj4];
            psd = *(const v4f*)&eDh[shl * NN + jbase + sj4];
        }
#pragma unroll
        for (int rr = 0; rr < 4; ++rr) {
            pe[rr * 2]     = edge[(i0 + w * 4 + rr) * NN + jbase + lane];
            pe[rr * 2 + 1] = edge[(i0 + w * 4 + rr) * NN + jbase + 64 + lane];
        }
    }
    *(uint4*)&Gt[0][r2][seg]      = pg0;
    *(uint4*)&Gt[0][r2 + 16][seg] = pg1;
    if (t < 128) {
        *(v4f*)&srB[0][shl][sj4] = psb;
        *(v4f*)&srD[0][shl][sj4] = psd;
    }
#pragma unroll
    for (int rr = 0; rr < 4; ++rr) {
        u64 b0 = __ballot(pe[rr * 2] != 0);
        u64 b1 = __ballot(pe[rr * 2 + 1] != 0);
        if (lane == 0)  { mrow[0][w * 4 + rr][0] = (u32)b0;         mrow[0][w * 4 + rr][2] = (u32)b1; }
        if (lane == 32) { mrow[0][w * 4 + rr][1] = (u32)(b0 >> 32); mrow[0][w * 4 + rr][3] = (u32)(b1 >> 32); }
    }
    __syncthreads();

    v4f acc = {0.f, 0.f, 0.f, 0.f};
    const int NCHK = (NN / NJS) / 128;   // 8

    for (int c = 0; c < NCHK; ++c) {
        const int cb = c & 1, nb = cb ^ 1;
        const bool pf = (c + 1) < NCHK;
        if (pf) {
            const int j0 = jbase + (c + 1) * 128;
            pg0 = *(const uint4*)&gTh[r2 * NN + j0 + seg];
            pg1 = *(const uint4*)&gTh[(r2 + 16) * NN + j0 + seg];
            if (t < 128) {
                psb = *(const v4f*)&eBh[shl * NN + j0 + sj4];
                psd = *(const v4f*)&eDh[shl * NN + j0 + sj4];
            }
#pragma unroll
            for (int rr = 0; rr < 4; ++rr) {
                pe[rr * 2]     = edge[(i0 + w * 4 + rr) * NN + j0 + lane];
                pe[rr * 2 + 1] = edge[(i0 + w * 4 + rr) * NN + j0 + 64 + lane];
            }
        }
        // ---- compute: 4 sub-chunks of 32 j; NO transcendentals ----
        const int brow = (ml < 8) ? (w * 8 + ml) : 32;
#pragma unroll
        for (int s = 0; s < 4; ++s) {
            const v4f b0 = *(const v4f*)&srB[cb][w][s * 32 + quad * 8];
            const v4f b1 = *(const v4f*)&srB[cb][w][s * 32 + quad * 8 + 4];
            const v4f d0 = *(const v4f*)&srD[cb][w][s * 32 + quad * 8];
            const v4f d1 = *(const v4f*)&srD[cb][w][s * 32 + quad * 8 + 4];
            const u32 mw = mrow[cb][ml][s] >> (quad * 8);
            const bf16x8 bfrag = *(const bf16x8*)&Gt[cb][brow][s * 32 + quad * 8];

            float p[8];
            p[0] = (mw & 1u)   ? fmaxf(Ai * b0.x, Ci * d0.x) : 0.f;
            p[1] = (mw & 2u)   ? fmaxf(Ai * b0.y, Ci * d0.y) : 0.f;
            p[2] = (mw & 4u)   ? fmaxf(Ai * b0.z, Ci * d0.z) : 0.f;
            p[3] = (mw & 8u)   ? fmaxf(Ai * b0.w, Ci * d0.w) : 0.f;
            p[4] = (mw & 16u)  ? fmaxf(Ai * b1.x, Ci * d1.x) : 0.f;
            p[5] = (mw & 32u)  ? fmaxf(Ai * b1.y, Ci * d1.y) : 0.f;
            p[6] = (mw & 64u)  ? fmaxf(Ai * b1.z, Ci * d1.z) : 0.f;
            p[7] = (mw & 128u) ? fmaxf(Ai * b1.w, Ci * d1.w) : 0.f;
            // truncating bf16 pack: one v_perm per pair
            u32 w01 = __builtin_amdgcn_perm(__float_as_uint(p[1]), __float_as_uint(p[0]), 0x07060302u);
            u32 w23 = __builtin_amdgcn_perm(__float_as_uint(p[3]), __float_as_uint(p[2]), 0x07060302u);
            u32 w45 = __builtin_amdgcn_perm(__float_as_uint(p[5]), __float_as_uint(p[4]), 0x07060302u);
            u32 w67 = __builtin_amdgcn_perm(__float_as_uint(p[7]), __float_as_uint(p[6]), 0x07060302u);
            uint4 au = {w01, w23, w45, w67};
            const bf16x8 afrag = *(const bf16x8*)&au;
            acc = __builtin_amdgcn_mfma_f32_16x16x32_bf16(afrag, bfrag, acc, 0, 0, 0);
        }
        if (pf) {
            *(uint4*)&Gt[nb][r2][seg]      = pg0;
            *(uint4*)&Gt[nb][r2 + 16][seg] = pg1;
            if (t < 128) {
                *(v4f*)&srB[nb][shl][sj4] = psb;
                *(v4f*)&srD[nb][shl][sj4] = psd;
            }
#pragma unroll
            for (int rr = 0; rr < 4; ++rr) {
                u64 b0 = __ballot(pe[rr * 2] != 0);
                u64 b1 = __ballot(pe[rr * 2 + 1] != 0);
                if (lane == 0)  { mrow[nb][w * 4 + rr][0] = (u32)b0;         mrow[nb][w * 4 + rr][2] = (u32)b1; }
                if (lane == 32) { mrow[nb][w * 4 + rr][1] = (u32)(b0 >> 32); mrow[nb][w * 4 + rr][3] = (u32)(b1 >> 32); }
            }
        }
        __syncthreads();
    }

    // C layout: col = ml (0..7 dims, 8 = denominator), row = quad*4 + r
    float* nw = numw + (size_t)js * NN * HD;
    float* dw = denw + (size_t)js * NN * NH;
    const int iA = i0 + quad * 4;
#pragma unroll
    for (int r = 0; r < 4; ++r) {
        if (ml < 8)       nw[(iA + r) * HD + h * 8 + ml] = acc[r];
        else if (ml == 8) dw[(iA + r) * NH + h]          = acc[r];
    }
}

// ---------------- kernel 3: combine j-split partials, div, ELU ---------------
__global__ __launch_bounds__(256) void k_comb(
    const float* __restrict__ numw, const float* __restrict__ denw,
    float* __restrict__ out)
{
    const int gid = blockIdx.x * 256 + threadIdx.x;   // 0 .. NN*HD-1
    const int i = gid >> 6, h = (gid & 63) >> 3;
    float num = 0.f, den = 0.f;
#pragma unroll
    for (int s = 0; s < NJS; ++s) {
        num += numw[s * NN * HD + gid];
        den += denw[s * NN * NH + i * NH + h];
    }
    float x = num / den;
    out[gid] = (x > 0.f) ? x : (__expf(x) - 1.f);     // ELU
}

extern "C" void kernel_launch(void* const* d_in, const int* in_sizes, int n_in,
                              void* d_out, int out_size, void* d_ws, size_t ws_size,
                              hipStream_t stream) {
    const float* vert = (const float*)d_in[0];
    const int*   edge = (const int*)d_in[1];
    const float* W    = (const float*)d_in[2];
    const float* al   = (const float*)d_in[3];
    const float* ar   = (const float*)d_in[4];
    float* out = (float*)d_out;

    char* ws = (char*)d_ws;
    short*  gT   = (short*)ws;                          // 512 KB
    float2* eAC  = (float2*)(ws + 512 * 1024);          // 256 KB
    float*  eB   = (float*)(ws + 768 * 1024);           // 128 KB
    float*  eD   = (float*)(ws + 896 * 1024);           // 128 KB
    short*  Wt   = (short*)(ws + 1024 * 1024);          // 184 KB
    float*  numw = (float*)(ws + 1280 * 1024);          // 4 MB (4 splits)
    float*  denw = (float*)(ws + 5376 * 1024);          // 512 KB

    hipLaunchKernelGGL(k_wprep, dim3(23), dim3(256), 0, stream, W, Wt);
    hipLaunchKernelGGL(k_gemm, dim3(NN / 16), dim3(256), 0, stream,
                       vert, Wt, al, ar, gT, eAC, eB, eD);
    hipLaunchKernelGGL(k_attn, dim3(NN / 16, 2, NJS), dim3(256), 0, stream,
                       edge, gT, eAC, eB, eD, numw, denw);
    hipLaunchKernelGGL(k_comb, dim3(NN * HD / 256), dim3(256), 0, stream,
                       numw, denw, out);
}